// Round 3
// baseline (116.052 us; speedup 1.0000x reference)
//
#include <hip/hip_runtime.h>

// Chamfer loss: x [B,N,D], y [B,M,D], D=3, fp32.
// dist[b,m,n] = ||x[b,n]-y[b,m]||^2
// row[b] = mean_n min_m dist ; col[b] = mean_m min_n dist
// out = mean_b max(row, col)
//
// R3: single fused kernel (2 dispatches total incl. memset).
// - 512 blocks = 2 dirs x 32 batches x 8 target-chunks, 256 threads.
// - Each thread register-blocks 8 queries (block covers ALL 2048 queries),
//   scans its 256-target chunk from LDS: 1 broadcast ds_read_b128 feeds
//   8 x (3 fma + 0.5 min3) VALU ops.
// - Cross-chunk combine: order-preserving-key atomicMin into minkeys[].
// - Last block per (dir,b) (arrival counter) reduces its segment using its
//   own in-register ||q||^2; last (dir,b) overall computes the final scalar.

#define BATCH   32
#define NPTS    2048
#define THREADS 256
#define QPT     8              // 256*8 = 2048 queries per block
#define TCH     8              // target chunks per (dir,batch)
#define TC      (NPTS / TCH)   // 256 targets per chunk
#define NSEG    (2 * BATCH)    // 64 (dir,batch) segments

// workspace layout (one 0xFF memset covers minkeys+counters+done)
#define OFF_MINKEYS   0
#define OFF_COUNTERS  (NSEG * NPTS * 4)          // 524288
#define OFF_DONE      (OFF_COUNTERS + NSEG * 4)  // 524544
#define MEMSET_BYTES  (OFF_DONE + 4)             // 524548
#define OFF_SUMS      (OFF_DONE + 256)           // 524800 (not memset; atomicExch'd)

// order-preserving float -> unsigned key (min-compatible)
__device__ __forceinline__ unsigned fkey(float f) {
    unsigned u = __float_as_uint(f);
    return u ^ ((unsigned)((int)u >> 31) | 0x80000000u);
}
__device__ __forceinline__ float keyToFloat(unsigned k) {
    unsigned u = (k & 0x80000000u) ? (k ^ 0x80000000u) : ~k;
    return __uint_as_float(u);
}

__global__ __launch_bounds__(THREADS) void chamfer_fused(
    const float* __restrict__ x, const float* __restrict__ y,
    unsigned* __restrict__ minkeys,   // [NSEG*NPTS], init 0xFFFFFFFF
    unsigned* __restrict__ counters,  // [NSEG], init 0xFFFFFFFF
    unsigned* __restrict__ done,      // [1], init 0xFFFFFFFF
    float* __restrict__ sums,         // [NSEG], written via atomicExch
    float* __restrict__ out)
{
    __shared__ float4 t4[TC];             // (tx,ty,tz, 0.5*||t||^2) — 4 KB
    __shared__ float wsum[THREADS / 64];
    __shared__ int flagRed, flagLast;

    const int blk   = blockIdx.x;         // 512
    const int dir   = blk >> 8;
    const int r     = blk & 255;
    const int b     = r >> 3;
    const int chunk = r & 7;
    const int g     = dir * BATCH + b;

    const float* q = (dir == 0 ? x : y) + (size_t)b * NPTS * 3;
    const float* t = (dir == 0 ? y : x) + (size_t)b * NPTS * 3;

    // Stage this chunk's targets with precomputed h = 0.5*||t||^2.
    for (int j = threadIdx.x; j < TC; j += THREADS) {
        int jj = chunk * TC + j;
        float tx = t[3 * jj + 0];
        float ty = t[3 * jj + 1];
        float tz = t[3 * jj + 2];
        t4[j] = make_float4(tx, ty, tz, 0.5f * (tx * tx + ty * ty + tz * tz));
    }

    // 8 query points per thread (covers all 2048 queries per block).
    float qx[QPT], qy[QPT], qz[QPT], mn[QPT];
#pragma unroll
    for (int k = 0; k < QPT; ++k) {
        int qi = threadIdx.x + k * THREADS;
        qx[k] = q[3 * qi + 0];
        qy[k] = q[3 * qi + 1];
        qz[k] = q[3 * qi + 2];
        mn[k] = 3.4e38f;
    }
    __syncthreads();

    // min over chunk targets of s = h_t - q.t  (dist = 2s + ||q||^2, monotone)
#pragma unroll 4
    for (int j = 0; j < TC; j += 2) {
        float4 a = t4[j];
        float4 c = t4[j + 1];
#pragma unroll
        for (int k = 0; k < QPT; ++k) {
            float s0 = fmaf(-qz[k], a.z, fmaf(-qy[k], a.y, fmaf(-qx[k], a.x, a.w)));
            float s1 = fmaf(-qz[k], c.z, fmaf(-qy[k], c.y, fmaf(-qx[k], c.x, c.w)));
            mn[k] = fminf(fminf(mn[k], s0), s1);   // v_min3_f32
        }
    }

    // Cross-chunk combine.
    unsigned* base = minkeys + (size_t)g * NPTS;
#pragma unroll
    for (int k = 0; k < QPT; ++k)
        atomicMin(&base[threadIdx.x + k * THREADS], fkey(mn[k]));

    __threadfence();
    __syncthreads();
    if (threadIdx.x == 0) {
        unsigned old = atomicAdd(&counters[g], 1u);      // init -1: last returns TCH-2
        flagRed = (old == (unsigned)(TCH - 2));
    }
    __syncthreads();
    if (!flagRed) return;

    // ---- last block for (dir,b): reduce its segment to sums[g] ----
    __threadfence();   // acquire: see peers' atomicMin results
    float acc = 0.0f;
#pragma unroll
    for (int k = 0; k < QPT; ++k) {
        int qi = threadIdx.x + k * THREADS;
        unsigned kk = atomicOr(&base[qi], 0u);           // coherent read
        float s = keyToFloat(kk);
        acc += fmaf(2.0f, s, qx[k] * qx[k] + qy[k] * qy[k] + qz[k] * qz[k]);
    }
    for (int off = 32; off > 0; off >>= 1)
        acc += __shfl_down(acc, off);
    if ((threadIdx.x & 63) == 0) wsum[threadIdx.x >> 6] = acc;
    __syncthreads();
    if (threadIdx.x == 0) {
        float tot = wsum[0] + wsum[1] + wsum[2] + wsum[3];
        atomicExch(&sums[g], tot);                       // coherent publish
        __threadfence();
        unsigned old2 = atomicAdd(done, 1u);             // init -1: last returns NSEG-2
        flagLast = (old2 == (unsigned)(NSEG - 2));
    }
    __syncthreads();
    if (!flagLast) return;

    // ---- very last block: final scalar ----
    __threadfence();
    if (threadIdx.x < 64) {
        float v = 0.0f;
        if (threadIdx.x < BATCH) {
            float row = atomicAdd(&sums[threadIdx.x], 0.0f);          // coherent read
            float col = atomicAdd(&sums[BATCH + threadIdx.x], 0.0f);
            v = fmaxf(row, col) * (1.0f / NPTS);
        }
        for (int off = 32; off > 0; off >>= 1)
            v += __shfl_down(v, off);
        if (threadIdx.x == 0) out[0] = v * (1.0f / BATCH);
    }
}

extern "C" void kernel_launch(void* const* d_in, const int* in_sizes, int n_in,
                              void* d_out, int out_size, void* d_ws, size_t ws_size,
                              hipStream_t stream) {
    const float* x = (const float*)d_in[0];
    const float* y = (const float*)d_in[1];
    float* out = (float*)d_out;

    char* ws = (char*)d_ws;
    unsigned* minkeys  = (unsigned*)(ws + OFF_MINKEYS);
    unsigned* counters = (unsigned*)(ws + OFF_COUNTERS);
    unsigned* done     = (unsigned*)(ws + OFF_DONE);
    float*    sums     = (float*)(ws + OFF_SUMS);

    // One fill arms everything: minkeys = max-key, counters/done = -1.
    hipMemsetAsync(ws, 0xFF, MEMSET_BYTES, stream);

    chamfer_fused<<<2 * BATCH * TCH, THREADS, 0, stream>>>(
        x, y, minkeys, counters, done, sums, out);
}

// Round 4
// 87.132 us; speedup vs baseline: 1.3319x; 1.3319x over previous
//
#include <hip/hip_runtime.h>

// Chamfer loss: x [B,N,D], y [B,M,D], D=3, fp32.
// dist[b,m,n] = ||x[b,n]-y[b,m]||^2
// row[b] = mean_n min_m dist ; col[b] = mean_m min_n dist
// out = mean_b max(row, col)
//
// R4: 3 dispatches, no memsets, no atomics.
//  K1: 2048 blocks (2 dir x 32 batch x 32 target-chunks), 256 thr, QPT=8.
//      Register-block 8 queries/thread (block covers all 2048 queries),
//      scan 64-target LDS chunk, write partial mins [seg][chunk][query].
//      8 blocks/CU -> 8 waves/SIMD to hide LDS/global latency.
//  K2: 512 blocks: min over 32 chunks per query, finish dist, block sums.
//  K3: 1 wave: per-seg totals, max(row,col), mean -> out.

#define BATCH   32
#define NPTS    2048
#define THREADS 256
#define QPT     8              // 256*8 = 2048 queries per block
#define TCH     32             // target chunks per (dir,batch)
#define TC      (NPTS / TCH)   // 64 targets per chunk
#define NSEG    (2 * BATCH)    // 64 segments
#define CBLK    8              // combine blocks per segment

__global__ __launch_bounds__(THREADS, 8) void chamfer_min(
    const float* __restrict__ x, const float* __restrict__ y,
    float* __restrict__ part /* [NSEG][TCH][NPTS] */)
{
    __shared__ float4 t4[TC];   // (tx,ty,tz, 0.5*||t||^2) — 1 KB

    const int blk   = blockIdx.x;      // 2048
    const int dir   = blk >> 10;
    const int r     = blk & 1023;
    const int b     = r >> 5;
    const int chunk = r & 31;

    const float* q = (dir == 0 ? x : y) + (size_t)b * NPTS * 3;
    const float* t = (dir == 0 ? y : x) + (size_t)b * NPTS * 3;

    // Stage this chunk's 64 targets with precomputed h = 0.5*||t||^2.
    if (threadIdx.x < TC) {
        int jj = chunk * TC + threadIdx.x;
        float tx = t[3 * jj + 0];
        float ty = t[3 * jj + 1];
        float tz = t[3 * jj + 2];
        t4[threadIdx.x] = make_float4(tx, ty, tz, 0.5f * (tx * tx + ty * ty + tz * tz));
    }

    // 8 query points per thread (covers all 2048 queries per block).
    float qx[QPT], qy[QPT], qz[QPT], mn[QPT];
#pragma unroll
    for (int k = 0; k < QPT; ++k) {
        int qi = threadIdx.x + k * THREADS;
        qx[k] = q[3 * qi + 0];
        qy[k] = q[3 * qi + 1];
        qz[k] = q[3 * qi + 2];
        mn[k] = 3.4e38f;
    }
    __syncthreads();

    // min over chunk targets of s = h_t - q.t  (dist = 2s + ||q||^2, monotone)
#pragma unroll 4
    for (int j = 0; j < TC; j += 2) {
        float4 a = t4[j];
        float4 c = t4[j + 1];
#pragma unroll
        for (int k = 0; k < QPT; ++k) {
            float s0 = fmaf(-qz[k], a.z, fmaf(-qy[k], a.y, fmaf(-qx[k], a.x, a.w)));
            float s1 = fmaf(-qz[k], c.z, fmaf(-qy[k], c.y, fmaf(-qx[k], c.x, c.w)));
            mn[k] = fminf(fminf(mn[k], s0), s1);   // v_min3_f32
        }
    }

    // Plain coalesced partial writes — no init, no atomics.
    float* pbase = part + ((size_t)(dir * BATCH + b) * TCH + chunk) * NPTS;
#pragma unroll
    for (int k = 0; k < QPT; ++k)
        pbase[threadIdx.x + k * THREADS] = mn[k];
}

__global__ __launch_bounds__(THREADS) void chamfer_combine(
    const float* __restrict__ x, const float* __restrict__ y,
    const float* __restrict__ part,
    float* __restrict__ blocksums /* [NSEG*CBLK] */)
{
    __shared__ float wsum[THREADS / 64];

    const int blk = blockIdx.x;        // 512 = NSEG * CBLK
    const int seg = blk >> 3;
    const int qc  = blk & 7;
    const int dir = seg >> 5;
    const int b   = seg & 31;
    const int qi  = qc * THREADS + threadIdx.x;

    // min over the 32 chunk partials (wave-coalesced strided loads)
    const float* p = part + (size_t)seg * TCH * NPTS + qi;
    float mn = p[0];
#pragma unroll
    for (int c = 1; c < TCH; ++c)
        mn = fminf(mn, p[(size_t)c * NPTS]);

    const float* q = (dir == 0 ? x : y) + (size_t)b * NPTS * 3 + 3 * qi;
    float qx = q[0], qy = q[1], qz = q[2];
    float d = fmaf(2.0f, mn, qx * qx + qy * qy + qz * qz);

    for (int off = 32; off > 0; off >>= 1)
        d += __shfl_down(d, off);
    if ((threadIdx.x & 63) == 0) wsum[threadIdx.x >> 6] = d;
    __syncthreads();
    if (threadIdx.x == 0)
        blocksums[blk] = wsum[0] + wsum[1] + wsum[2] + wsum[3];
}

__global__ void chamfer_finalize(const float* __restrict__ blocksums,
                                 float* __restrict__ out)
{
    const int lane = threadIdx.x;   // 64 threads: lane = seg
    float s = 0.0f;
#pragma unroll
    for (int i = 0; i < CBLK; ++i)
        s += blocksums[lane * CBLK + i];
    // lane < 32: row for batch=lane ; lane >= 32: col for batch=lane-32
    float other = __shfl(s, lane + 32);      // valid where lane < 32
    float v = (lane < 32) ? fmaxf(s, other) * (1.0f / NPTS) : 0.0f;
    for (int off = 16; off > 0; off >>= 1)
        v += __shfl_down(v, off);
    if (lane == 0) out[0] = v * (1.0f / BATCH);
}

extern "C" void kernel_launch(void* const* d_in, const int* in_sizes, int n_in,
                              void* d_out, int out_size, void* d_ws, size_t ws_size,
                              hipStream_t stream) {
    const float* x = (const float*)d_in[0];
    const float* y = (const float*)d_in[1];
    float* out = (float*)d_out;

    float* part      = (float*)d_ws;                               // 16 MB
    float* blocksums = part + (size_t)NSEG * TCH * NPTS;           // 2 KB

    chamfer_min<<<2 * BATCH * TCH, THREADS, 0, stream>>>(x, y, part);
    chamfer_combine<<<NSEG * CBLK, THREADS, 0, stream>>>(x, y, part, blocksums);
    chamfer_finalize<<<1, 64, 0, stream>>>(blocksums, out);
}